// Round 6
// baseline (53.321 us; speedup 1.0000x reference)
//
#include <hip/hip_runtime.h>
#include <math.h>

namespace {

constexpr int kL       = 2048;  // sequence length
constexpr int kThreads = 512;   // 8 waves
constexpr int kBlkPos  = 64;    // 8 waves x 8 positions per block

typedef float    vfloat4 __attribute__((ext_vector_type(4)));
typedef _Float16 half4   __attribute__((ext_vector_type(4)));

// x += dpp_move(x); all-VALU, no LDS.
template <int CTRL, int RM, bool BC>
__device__ __forceinline__ float dpp_acc(float x) {
    const int y = __builtin_amdgcn_update_dpp(0, __float_as_int(x), CTRL, RM, 0xF, BC);
    return x + __int_as_float(y);
}

// Full 64-lane sum, result broadcast via readlane(63).
__device__ __forceinline__ float wave_sum(float x) {
    x = dpp_acc<0xB1,  0xF, true >(x);  // quad_perm xor1
    x = dpp_acc<0x4E,  0xF, true >(x);  // quad_perm xor2
    x = dpp_acc<0x124, 0xF, true >(x);  // row_ror:4
    x = dpp_acc<0x128, 0xF, true >(x);  // row_ror:8 -> row sums
    x = dpp_acc<0x142, 0xA, false>(x);  // row_bcast15 -> rows 1,3
    x = dpp_acc<0x143, 0xC, false>(x);  // row_bcast31 -> row 3 = total
    return __int_as_float(__builtin_amdgcn_readlane(__float_as_int(x), 63));
}

__device__ __forceinline__ int wrow(int t, int c) {  // weight-table row
    return (c == 5) ? 75 : (t * 5 + c);
}

// One wave per position (8 consecutive positions per wave). fp16 weight table
// in LDS: row = tap*5+class, row 75 = zeros (sentinel). S1[r] = sum over the
// 256 channels of row r -> mean needs NO cross-lane reduce (15 broadcast
// reads); only E[h^2] uses the DPP chain. Mask folded analytically.
__global__ __launch_bounds__(kThreads, 4)
void cnn_emb_ln(const int*   __restrict__ ids,     // [B*L] tokens 0..5
                const float* __restrict__ mask,    // [B*L]
                const float* __restrict__ W3,      // [256][5][3]
                const float* __restrict__ W5,      // [256][5][5]
                const float* __restrict__ W7,      // [256][5][7]
                const float* __restrict__ gamma,   // [768]
                const float* __restrict__ beta,    // [768]
                float*       __restrict__ out)     // [B*L][768]
{
    __shared__ half4 sW[76][64];      // 38912 B
    __shared__ float sS1p[76][4];     // row-sum partials
    __shared__ float sS1[76];         // per-row channel sums (fp32)

    const int tid  = threadIdx.x;
    const int lane = tid & 63;
    const int wave = tid >> 6;

    // ---- stage weights: coalesced float4 reads, scattered fp16 LDS writes ----
    _Float16* sWh = reinterpret_cast<_Float16*>(sW);
    if (tid < 256) sWh[75 * 256 + tid] = (_Float16)0.f;     // zero sentinel row

    {   // W3: 3840 floats, taps 0..2
        const float4* v4 = reinterpret_cast<const float4*>(W3);
        for (int i = tid; i < 960; i += kThreads) {
            const float4 v = v4[i];
            const float f[4] = {v.x, v.y, v.z, v.w};
            #pragma unroll
            for (int j = 0; j < 4; ++j) {
                const int e = 4 * i + j, o = e / 15, r = e % 15;
                sWh[((r % 3) * 5 + (r / 3)) * 256 + o] = (_Float16)f[j];
            }
        }
    }
    {   // W5: 6400 floats, taps 3..7
        const float4* v4 = reinterpret_cast<const float4*>(W5);
        for (int i = tid; i < 1600; i += kThreads) {
            const float4 v = v4[i];
            const float f[4] = {v.x, v.y, v.z, v.w};
            #pragma unroll
            for (int j = 0; j < 4; ++j) {
                const int e = 4 * i + j, o = e / 25, r = e % 25;
                sWh[((3 + r % 5) * 5 + (r / 5)) * 256 + o] = (_Float16)f[j];
            }
        }
    }
    {   // W7: 8960 floats, taps 8..14
        const float4* v4 = reinterpret_cast<const float4*>(W7);
        for (int i = tid; i < 2240; i += kThreads) {
            const float4 v = v4[i];
            const float f[4] = {v.x, v.y, v.z, v.w};
            #pragma unroll
            for (int j = 0; j < 4; ++j) {
                const int e = 4 * i + j, o = e / 35, r = e % 35;
                sWh[((8 + r % 7) * 5 + (r / 7)) * 256 + o] = (_Float16)f[j];
            }
        }
    }

    // ---- per-wave id halo (14) + mask (8) into lane registers ----
    const int p0 = blockIdx.x * kBlkPos + wave * 8;   // first position of wave
    const int l0 = p0 & (kL - 1);

    int myc = 5;
    if (lane < 14) {
        const int lp = l0 - 3 + lane;
        if (lp >= 0 && lp < kL) {
            const int v = ids[p0 - 3 + lane];
            myc = (v < 5) ? v : 5;
        }
    }
    float mym = 0.f;
    if (lane < 8) mym = mask[p0 + lane];

    // per-lane gamma/beta, fp32 in registers
    float ga[3][4], be[3][4];
    #pragma unroll
    for (int g = 0; g < 3; ++g) {
        const float4 gg = *reinterpret_cast<const float4*>(gamma + g * 256 + 4 * lane);
        const float4 bb = *reinterpret_cast<const float4*>(beta  + g * 256 + 4 * lane);
        ga[g][0] = gg.x; ga[g][1] = gg.y; ga[g][2] = gg.z; ga[g][3] = gg.w;
        be[g][0] = bb.x; be[g][1] = bb.y; be[g][2] = bb.z; be[g][3] = bb.w;
    }

    __syncthreads();

    // ---- S1: per-row channel sums (76 rows x 4 segments of 16 half4) ----
    if (tid < 304) {
        const int r = tid >> 2, seg = tid & 3;
        half4 acc = {(_Float16)0.f, (_Float16)0.f, (_Float16)0.f, (_Float16)0.f};
        #pragma unroll
        for (int q = 0; q < 16; ++q) acc = acc + sW[r][seg * 16 + q];
        sS1p[r][seg] = ((float)acc.x + (float)acc.y) + ((float)acc.z + (float)acc.w);
    }
    __syncthreads();
    if (tid < 76)
        sS1[tid] = (sS1p[tid][0] + sS1p[tid][1]) + (sS1p[tid][2] + sS1p[tid][3]);
    __syncthreads();

    #pragma unroll
    for (int i = 0; i < 8; ++i) {
        // wave-uniform window classes + mask via readlane (immediate lanes)
        int c[7];
        #pragma unroll
        for (int j = 0; j < 7; ++j) c[j] = __builtin_amdgcn_readlane(myc, i + j);
        const float m = __int_as_float(__builtin_amdgcn_readlane(__float_as_int(mym), i));

        // row indices, shared by the weight table and the S1 table
        const int r0  = wrow(0,  c[2]), r1  = wrow(1,  c[3]), r2  = wrow(2,  c[4]);
        const int r3  = wrow(3,  c[1]), r4  = wrow(4,  c[2]), r5  = wrow(5,  c[3]);
        const int r6  = wrow(6,  c[4]), r7  = wrow(7,  c[5]);
        const int r8  = wrow(8,  c[0]), r9  = wrow(9,  c[1]), r10 = wrow(10, c[2]);
        const int r11 = wrow(11, c[3]), r12 = wrow(12, c[4]), r13 = wrow(13, c[5]);
        const int r14 = wrow(14, c[6]);

        // branchless tap accumulation, packed fp16
        const half4 a3 =  sW[r0][lane] + sW[r1][lane] + sW[r2][lane];
        const half4 a5 = (sW[r3][lane] + sW[r4][lane])
                       + (sW[r5][lane] + sW[r6][lane]) + sW[r7][lane];
        const half4 a7 = ((sW[r8][lane]  + sW[r9][lane])
                       +  (sW[r10][lane] + sW[r11][lane]))
                       + ((sW[r12][lane] + sW[r13][lane]) + sW[r14][lane]);

        // sum(h) over 768 channels: 15 broadcast LDS reads, no cross-lane op
        const float s_tot =
            (((sS1[r0]  + sS1[r1])  + (sS1[r2]  + sS1[r3]))
           + ((sS1[r4]  + sS1[r5])  + (sS1[r6]  + sS1[r7])))
          + (((sS1[r8]  + sS1[r9])  + (sS1[r10] + sS1[r11]))
           + ((sS1[r12] + sS1[r13]) +  sS1[r14]));

        const float h3[4] = {(float)a3.x, (float)a3.y, (float)a3.z, (float)a3.w};
        const float h5[4] = {(float)a5.x, (float)a5.y, (float)a5.z, (float)a5.w};
        const float h7[4] = {(float)a7.x, (float)a7.y, (float)a7.z, (float)a7.w};

        // per-lane sum of squares: 3 parallel fma chains
        float ss0 = fmaf(h3[1], h3[1], h3[0] * h3[0]);
        ss0 = fmaf(h3[2], h3[2], ss0); ss0 = fmaf(h3[3], h3[3], ss0);
        float ss1 = fmaf(h5[1], h5[1], h5[0] * h5[0]);
        ss1 = fmaf(h5[2], h5[2], ss1); ss1 = fmaf(h5[3], h5[3], ss1);
        float ss2 = fmaf(h7[1], h7[1], h7[0] * h7[0]);
        ss2 = fmaf(h7[2], h7[2], ss2); ss2 = fmaf(h7[3], h7[3], ss2);

        const float ss_tot = wave_sum((ss0 + ss1) + ss2);

        const float inv_n = 1.0f / 768.0f;
        const float mu  = m * s_tot * inv_n;
        const float ex2 = (m * m) * ss_tot * inv_n;
        const float var = fmaxf(ex2 - mu * mu, 0.0f);
        const float rs  = rsqrtf(var + 1e-12f);
        const float aa  = m * rs;          // (m*h - mu)*rs = h*aa + cc
        const float cc  = -mu * rs;

        float* o = out + (size_t)(p0 + i) * 768 + 4 * lane;

        vfloat4 r;
        r.x = fmaf(fmaf(h3[0], aa, cc), ga[0][0], be[0][0]);
        r.y = fmaf(fmaf(h3[1], aa, cc), ga[0][1], be[0][1]);
        r.z = fmaf(fmaf(h3[2], aa, cc), ga[0][2], be[0][2]);
        r.w = fmaf(fmaf(h3[3], aa, cc), ga[0][3], be[0][3]);
        __builtin_nontemporal_store(r, reinterpret_cast<vfloat4*>(o));

        r.x = fmaf(fmaf(h5[0], aa, cc), ga[1][0], be[1][0]);
        r.y = fmaf(fmaf(h5[1], aa, cc), ga[1][1], be[1][1]);
        r.z = fmaf(fmaf(h5[2], aa, cc), ga[1][2], be[1][2]);
        r.w = fmaf(fmaf(h5[3], aa, cc), ga[1][3], be[1][3]);
        __builtin_nontemporal_store(r, reinterpret_cast<vfloat4*>(o + 256));

        r.x = fmaf(fmaf(h7[0], aa, cc), ga[2][0], be[2][0]);
        r.y = fmaf(fmaf(h7[1], aa, cc), ga[2][1], be[2][1]);
        r.z = fmaf(fmaf(h7[2], aa, cc), ga[2][2], be[2][2]);
        r.w = fmaf(fmaf(h7[3], aa, cc), ga[2][3], be[2][3]);
        __builtin_nontemporal_store(r, reinterpret_cast<vfloat4*>(o + 512));
    }
}

} // namespace

extern "C" void kernel_launch(void* const* d_in, const int* in_sizes, int n_in,
                              void* d_out, int out_size, void* d_ws, size_t ws_size,
                              hipStream_t stream) {
    const int*   ids   = (const int*)  d_in[0];
    const float* mask  = (const float*)d_in[1];
    const float* W3    = (const float*)d_in[2];
    const float* W5    = (const float*)d_in[3];
    const float* W7    = (const float*)d_in[4];
    const float* gamma = (const float*)d_in[5];
    const float* beta  = (const float*)d_in[6];
    float*       out   = (float*)d_out;

    const int npos = in_sizes[0];              // B*L = 65536
    const int grid = npos / kBlkPos;           // 1024 blocks; 2/CU -> 2 clean rounds

    hipLaunchKernelGGL(cnn_emb_ln, dim3(grid), dim3(kThreads), 0, stream,
                       ids, mask, W3, W5, W7, gamma, beta, out);
}

// Round 7
// 42.820 us; speedup vs baseline: 1.2452x; 1.2452x over previous
//
#include <hip/hip_runtime.h>
#include <math.h>

namespace {

constexpr int kL       = 2048;  // sequence length
constexpr int kThreads = 512;   // 8 waves
constexpr int kBlkPos  = 64;    // 8 waves x 8 positions per block

typedef float    vfloat4 __attribute__((ext_vector_type(4)));
typedef _Float16 half4   __attribute__((ext_vector_type(4)));

// x += dpp_move(x); all-VALU, no LDS.
template <int CTRL, int RM, bool BC>
__device__ __forceinline__ float dpp_acc(float x) {
    const int y = __builtin_amdgcn_update_dpp(0, __float_as_int(x), CTRL, RM, 0xF, BC);
    return x + __int_as_float(y);
}

// Full 64-lane sum, result broadcast via readlane(63).
__device__ __forceinline__ float wave_sum(float x) {
    x = dpp_acc<0xB1,  0xF, true >(x);  // quad_perm xor1
    x = dpp_acc<0x4E,  0xF, true >(x);  // quad_perm xor2
    x = dpp_acc<0x124, 0xF, true >(x);  // row_ror:4
    x = dpp_acc<0x128, 0xF, true >(x);  // row_ror:8 -> row sums
    x = dpp_acc<0x142, 0xA, false>(x);  // row_bcast15 -> rows 1,3
    x = dpp_acc<0x143, 0xC, false>(x);  // row_bcast31 -> row 3 = total
    return __int_as_float(__builtin_amdgcn_readlane(__float_as_int(x), 63));
}

__device__ __forceinline__ int wrow(int t, int c) {  // weight-table row
    return (c == 5) ? 75 : (t * 5 + c);
}

// One wave per position (8 consecutive positions per wave). Single fp16
// weight table in LDS: row = tap*5+class, row 75 = zeros (sentinel: token 5
// or out-of-range tap). Window classes distributed via readlane from a
// per-wave halo register. LayerNorm stats via DPP; mask folded analytically.
// R7: plain (L2-mediated) stores instead of nontemporal — A/B vs R5.
__global__ __launch_bounds__(kThreads, 4)
void cnn_emb_ln(const int*   __restrict__ ids,     // [B*L] tokens 0..5
                const float* __restrict__ mask,    // [B*L]
                const float* __restrict__ W3,      // [256][5][3]
                const float* __restrict__ W5,      // [256][5][5]
                const float* __restrict__ W7,      // [256][5][7]
                const float* __restrict__ gamma,   // [768]
                const float* __restrict__ beta,    // [768]
                float*       __restrict__ out)     // [B*L][768]
{
    __shared__ half4 sW[76][64];   // 38912 B

    const int tid  = threadIdx.x;
    const int lane = tid & 63;
    const int wave = tid >> 6;

    // ---- stage weights: coalesced float4 reads, scattered fp16 LDS writes ----
    _Float16* sWh = reinterpret_cast<_Float16*>(sW);
    if (tid < 256) sWh[75 * 256 + tid] = (_Float16)0.f;     // zero sentinel row

    {   // W3: 3840 floats, taps 0..2
        const float4* v4 = reinterpret_cast<const float4*>(W3);
        for (int i = tid; i < 960; i += kThreads) {
            const float4 v = v4[i];
            const float f[4] = {v.x, v.y, v.z, v.w};
            #pragma unroll
            for (int j = 0; j < 4; ++j) {
                const int e = 4 * i + j, o = e / 15, r = e % 15;
                sWh[((r % 3) * 5 + (r / 3)) * 256 + o] = (_Float16)f[j];
            }
        }
    }
    {   // W5: 6400 floats, taps 3..7
        const float4* v4 = reinterpret_cast<const float4*>(W5);
        for (int i = tid; i < 1600; i += kThreads) {
            const float4 v = v4[i];
            const float f[4] = {v.x, v.y, v.z, v.w};
            #pragma unroll
            for (int j = 0; j < 4; ++j) {
                const int e = 4 * i + j, o = e / 25, r = e % 25;
                sWh[((3 + r % 5) * 5 + (r / 5)) * 256 + o] = (_Float16)f[j];
            }
        }
    }
    {   // W7: 8960 floats, taps 8..14
        const float4* v4 = reinterpret_cast<const float4*>(W7);
        for (int i = tid; i < 2240; i += kThreads) {
            const float4 v = v4[i];
            const float f[4] = {v.x, v.y, v.z, v.w};
            #pragma unroll
            for (int j = 0; j < 4; ++j) {
                const int e = 4 * i + j, o = e / 35, r = e % 35;
                sWh[((8 + r % 7) * 5 + (r / 7)) * 256 + o] = (_Float16)f[j];
            }
        }
    }

    // ---- per-wave id halo (14) + mask (8) into lane registers ----
    const int p0 = blockIdx.x * kBlkPos + wave * 8;   // first position of wave
    const int l0 = p0 & (kL - 1);

    int myc = 5;
    if (lane < 14) {
        const int lp = l0 - 3 + lane;
        if (lp >= 0 && lp < kL) {
            const int v = ids[p0 - 3 + lane];
            myc = (v < 5) ? v : 5;
        }
    }
    float mym = 0.f;
    if (lane < 8) mym = mask[p0 + lane];

    // per-lane gamma/beta, fp32 in registers
    float ga[3][4], be[3][4];
    #pragma unroll
    for (int g = 0; g < 3; ++g) {
        const float4 gg = *reinterpret_cast<const float4*>(gamma + g * 256 + 4 * lane);
        const float4 bb = *reinterpret_cast<const float4*>(beta  + g * 256 + 4 * lane);
        ga[g][0] = gg.x; ga[g][1] = gg.y; ga[g][2] = gg.z; ga[g][3] = gg.w;
        be[g][0] = bb.x; be[g][1] = bb.y; be[g][2] = bb.z; be[g][3] = bb.w;
    }

    __syncthreads();

    #pragma unroll
    for (int i = 0; i < 8; ++i) {
        // wave-uniform window classes + mask via readlane (immediate lanes)
        int c[7];
        #pragma unroll
        for (int j = 0; j < 7; ++j) c[j] = __builtin_amdgcn_readlane(myc, i + j);
        const float m = __int_as_float(__builtin_amdgcn_readlane(__float_as_int(mym), i));

        // branchless tap accumulation, packed fp16
        const half4 a3 =  sW[wrow(0, c[2])][lane] + sW[wrow(1, c[3])][lane]
                       +  sW[wrow(2, c[4])][lane];
        const half4 a5 = (sW[wrow(3, c[1])][lane] + sW[wrow(4, c[2])][lane])
                       + (sW[wrow(5, c[3])][lane] + sW[wrow(6, c[4])][lane])
                       +  sW[wrow(7, c[5])][lane];
        const half4 a7 = ((sW[wrow( 8, c[0])][lane] + sW[wrow( 9, c[1])][lane])
                       +  (sW[wrow(10, c[2])][lane] + sW[wrow(11, c[3])][lane]))
                       + ((sW[wrow(12, c[4])][lane] + sW[wrow(13, c[5])][lane])
                       +   sW[wrow(14, c[6])][lane]);

        const float h3[4] = {(float)a3.x, (float)a3.y, (float)a3.z, (float)a3.w};
        const float h5[4] = {(float)a5.x, (float)a5.y, (float)a5.z, (float)a5.w};
        const float h7[4] = {(float)a7.x, (float)a7.y, (float)a7.z, (float)a7.w};

        // raw stats; mask folded in after the reduce
        float s = ((h3[0] + h3[1]) + (h3[2] + h3[3]))
                + ((h5[0] + h5[1]) + (h5[2] + h5[3]))
                + ((h7[0] + h7[1]) + (h7[2] + h7[3]));
        float ss = h3[0] * h3[0];
        ss = fmaf(h3[1], h3[1], ss); ss = fmaf(h3[2], h3[2], ss); ss = fmaf(h3[3], h3[3], ss);
        ss = fmaf(h5[0], h5[0], ss); ss = fmaf(h5[1], h5[1], ss); ss = fmaf(h5[2], h5[2], ss);
        ss = fmaf(h5[3], h5[3], ss); ss = fmaf(h7[0], h7[0], ss); ss = fmaf(h7[1], h7[1], ss);
        ss = fmaf(h7[2], h7[2], ss); ss = fmaf(h7[3], h7[3], ss);

        const float s_tot  = wave_sum(s);
        const float ss_tot = wave_sum(ss);

        const float inv_n = 1.0f / 768.0f;
        const float mu  = m * s_tot * inv_n;
        const float ex2 = (m * m) * ss_tot * inv_n;
        const float var = fmaxf(ex2 - mu * mu, 0.0f);
        const float rs  = rsqrtf(var + 1e-12f);
        const float aa  = m * rs;          // (m*h - mu)*rs = h*aa + cc
        const float cc  = -mu * rs;

        float* o = out + (size_t)(p0 + i) * 768 + 4 * lane;

        vfloat4 r;
        r.x = fmaf(fmaf(h3[0], aa, cc), ga[0][0], be[0][0]);
        r.y = fmaf(fmaf(h3[1], aa, cc), ga[0][1], be[0][1]);
        r.z = fmaf(fmaf(h3[2], aa, cc), ga[0][2], be[0][2]);
        r.w = fmaf(fmaf(h3[3], aa, cc), ga[0][3], be[0][3]);
        *reinterpret_cast<vfloat4*>(o) = r;

        r.x = fmaf(fmaf(h5[0], aa, cc), ga[1][0], be[1][0]);
        r.y = fmaf(fmaf(h5[1], aa, cc), ga[1][1], be[1][1]);
        r.z = fmaf(fmaf(h5[2], aa, cc), ga[1][2], be[1][2]);
        r.w = fmaf(fmaf(h5[3], aa, cc), ga[1][3], be[1][3]);
        *reinterpret_cast<vfloat4*>(o + 256) = r;

        r.x = fmaf(fmaf(h7[0], aa, cc), ga[2][0], be[2][0]);
        r.y = fmaf(fmaf(h7[1], aa, cc), ga[2][1], be[2][1]);
        r.z = fmaf(fmaf(h7[2], aa, cc), ga[2][2], be[2][2]);
        r.w = fmaf(fmaf(h7[3], aa, cc), ga[2][3], be[2][3]);
        *reinterpret_cast<vfloat4*>(o + 512) = r;
    }
}

} // namespace

extern "C" void kernel_launch(void* const* d_in, const int* in_sizes, int n_in,
                              void* d_out, int out_size, void* d_ws, size_t ws_size,
                              hipStream_t stream) {
    const int*   ids   = (const int*)  d_in[0];
    const float* mask  = (const float*)d_in[1];
    const float* W3    = (const float*)d_in[2];
    const float* W5    = (const float*)d_in[3];
    const float* W7    = (const float*)d_in[4];
    const float* gamma = (const float*)d_in[5];
    const float* beta  = (const float*)d_in[6];
    float*       out   = (float*)d_out;

    const int npos = in_sizes[0];              // B*L = 65536
    const int grid = npos / kBlkPos;           // 1024 blocks; 2/CU -> 2 clean rounds

    hipLaunchKernelGGL(cnn_emb_ln, dim3(grid), dim3(kThreads), 0, stream,
                       ids, mask, W3, W5, W7, gamma, beta, out);
}

// Round 8
// 42.138 us; speedup vs baseline: 1.2654x; 1.0162x over previous
//
#include <hip/hip_runtime.h>
#include <math.h>

namespace {

constexpr int kL       = 2048;  // sequence length
constexpr int kThreads = 512;   // 8 waves
constexpr int kBlkPos  = 128;   // 8 waves x 16 positions per block -> 512 blocks, ONE round
constexpr int kPosPerWave = 16;

typedef float    vfloat4 __attribute__((ext_vector_type(4)));
typedef _Float16 half4   __attribute__((ext_vector_type(4)));

// x += dpp_move(x); all-VALU, no LDS.
template <int CTRL, int RM, bool BC>
__device__ __forceinline__ float dpp_acc(float x) {
    const int y = __builtin_amdgcn_update_dpp(0, __float_as_int(x), CTRL, RM, 0xF, BC);
    return x + __int_as_float(y);
}

// Full 64-lane sum, result broadcast via readlane(63).
__device__ __forceinline__ float wave_sum(float x) {
    x = dpp_acc<0xB1,  0xF, true >(x);  // quad_perm xor1
    x = dpp_acc<0x4E,  0xF, true >(x);  // quad_perm xor2
    x = dpp_acc<0x124, 0xF, true >(x);  // row_ror:4
    x = dpp_acc<0x128, 0xF, true >(x);  // row_ror:8 -> row sums
    x = dpp_acc<0x142, 0xA, false>(x);  // row_bcast15 -> rows 1,3
    x = dpp_acc<0x143, 0xC, false>(x);  // row_bcast31 -> row 3 = total
    return __int_as_float(__builtin_amdgcn_readlane(__float_as_int(x), 63));
}

__device__ __forceinline__ int wrow(int t, int c) {  // weight-table row
    return (c == 5) ? 75 : (t * 5 + c);
}

// One wave per position (16 consecutive positions per wave). Single fp16
// weight table in LDS: row = tap*5+class, row 75 = zeros (sentinel: token 5
// or out-of-range tap). Window classes distributed via readlane from a
// per-wave halo register. LayerNorm stats via DPP; mask folded analytically.
// R8: single-residency-round geometry (512 blocks), otherwise identical to R7.
__global__ __launch_bounds__(kThreads, 4)
void cnn_emb_ln(const int*   __restrict__ ids,     // [B*L] tokens 0..5
                const float* __restrict__ mask,    // [B*L]
                const float* __restrict__ W3,      // [256][5][3]
                const float* __restrict__ W5,      // [256][5][5]
                const float* __restrict__ W7,      // [256][5][7]
                const float* __restrict__ gamma,   // [768]
                const float* __restrict__ beta,    // [768]
                float*       __restrict__ out)     // [B*L][768]
{
    __shared__ half4 sW[76][64];   // 38912 B

    const int tid  = threadIdx.x;
    const int lane = tid & 63;
    const int wave = tid >> 6;

    // ---- stage weights: coalesced float4 reads, scattered fp16 LDS writes ----
    _Float16* sWh = reinterpret_cast<_Float16*>(sW);
    if (tid < 256) sWh[75 * 256 + tid] = (_Float16)0.f;     // zero sentinel row

    {   // W3: 3840 floats, taps 0..2
        const float4* v4 = reinterpret_cast<const float4*>(W3);
        for (int i = tid; i < 960; i += kThreads) {
            const float4 v = v4[i];
            const float f[4] = {v.x, v.y, v.z, v.w};
            #pragma unroll
            for (int j = 0; j < 4; ++j) {
                const int e = 4 * i + j, o = e / 15, r = e % 15;
                sWh[((r % 3) * 5 + (r / 3)) * 256 + o] = (_Float16)f[j];
            }
        }
    }
    {   // W5: 6400 floats, taps 3..7
        const float4* v4 = reinterpret_cast<const float4*>(W5);
        for (int i = tid; i < 1600; i += kThreads) {
            const float4 v = v4[i];
            const float f[4] = {v.x, v.y, v.z, v.w};
            #pragma unroll
            for (int j = 0; j < 4; ++j) {
                const int e = 4 * i + j, o = e / 25, r = e % 25;
                sWh[((3 + r % 5) * 5 + (r / 5)) * 256 + o] = (_Float16)f[j];
            }
        }
    }
    {   // W7: 8960 floats, taps 8..14
        const float4* v4 = reinterpret_cast<const float4*>(W7);
        for (int i = tid; i < 2240; i += kThreads) {
            const float4 v = v4[i];
            const float f[4] = {v.x, v.y, v.z, v.w};
            #pragma unroll
            for (int j = 0; j < 4; ++j) {
                const int e = 4 * i + j, o = e / 35, r = e % 35;
                sWh[((8 + r % 7) * 5 + (r / 7)) * 256 + o] = (_Float16)f[j];
            }
        }
    }

    // ---- per-wave id halo (22) + mask (16) into lane registers ----
    const int p0 = blockIdx.x * kBlkPos + wave * kPosPerWave;  // first position of wave
    const int l0 = p0 & (kL - 1);

    int myc = 5;
    if (lane < kPosPerWave + 6) {
        const int lp = l0 - 3 + lane;
        if (lp >= 0 && lp < kL) {
            const int v = ids[p0 - 3 + lane];
            myc = (v < 5) ? v : 5;
        }
    }
    float mym = 0.f;
    if (lane < kPosPerWave) mym = mask[p0 + lane];

    // per-lane gamma/beta, fp32 in registers
    float ga[3][4], be[3][4];
    #pragma unroll
    for (int g = 0; g < 3; ++g) {
        const float4 gg = *reinterpret_cast<const float4*>(gamma + g * 256 + 4 * lane);
        const float4 bb = *reinterpret_cast<const float4*>(beta  + g * 256 + 4 * lane);
        ga[g][0] = gg.x; ga[g][1] = gg.y; ga[g][2] = gg.z; ga[g][3] = gg.w;
        be[g][0] = bb.x; be[g][1] = bb.y; be[g][2] = bb.z; be[g][3] = bb.w;
    }

    __syncthreads();

    #pragma unroll
    for (int i = 0; i < kPosPerWave; ++i) {
        // wave-uniform window classes + mask via readlane (immediate lanes)
        int c[7];
        #pragma unroll
        for (int j = 0; j < 7; ++j) c[j] = __builtin_amdgcn_readlane(myc, i + j);
        const float m = __int_as_float(__builtin_amdgcn_readlane(__float_as_int(mym), i));

        // branchless tap accumulation, packed fp16
        const half4 a3 =  sW[wrow(0, c[2])][lane] + sW[wrow(1, c[3])][lane]
                       +  sW[wrow(2, c[4])][lane];
        const half4 a5 = (sW[wrow(3, c[1])][lane] + sW[wrow(4, c[2])][lane])
                       + (sW[wrow(5, c[3])][lane] + sW[wrow(6, c[4])][lane])
                       +  sW[wrow(7, c[5])][lane];
        const half4 a7 = ((sW[wrow( 8, c[0])][lane] + sW[wrow( 9, c[1])][lane])
                       +  (sW[wrow(10, c[2])][lane] + sW[wrow(11, c[3])][lane]))
                       + ((sW[wrow(12, c[4])][lane] + sW[wrow(13, c[5])][lane])
                       +   sW[wrow(14, c[6])][lane]);

        const float h3[4] = {(float)a3.x, (float)a3.y, (float)a3.z, (float)a3.w};
        const float h5[4] = {(float)a5.x, (float)a5.y, (float)a5.z, (float)a5.w};
        const float h7[4] = {(float)a7.x, (float)a7.y, (float)a7.z, (float)a7.w};

        // raw stats; mask folded in after the reduce
        float s = ((h3[0] + h3[1]) + (h3[2] + h3[3]))
                + ((h5[0] + h5[1]) + (h5[2] + h5[3]))
                + ((h7[0] + h7[1]) + (h7[2] + h7[3]));
        float ss = h3[0] * h3[0];
        ss = fmaf(h3[1], h3[1], ss); ss = fmaf(h3[2], h3[2], ss); ss = fmaf(h3[3], h3[3], ss);
        ss = fmaf(h5[0], h5[0], ss); ss = fmaf(h5[1], h5[1], ss); ss = fmaf(h5[2], h5[2], ss);
        ss = fmaf(h5[3], h5[3], ss); ss = fmaf(h7[0], h7[0], ss); ss = fmaf(h7[1], h7[1], ss);
        ss = fmaf(h7[2], h7[2], ss); ss = fmaf(h7[3], h7[3], ss);

        const float s_tot  = wave_sum(s);
        const float ss_tot = wave_sum(ss);

        const float inv_n = 1.0f / 768.0f;
        const float mu  = m * s_tot * inv_n;
        const float ex2 = (m * m) * ss_tot * inv_n;
        const float var = fmaxf(ex2 - mu * mu, 0.0f);
        const float rs  = rsqrtf(var + 1e-12f);
        const float aa  = m * rs;          // (m*h - mu)*rs = h*aa + cc
        const float cc  = -mu * rs;

        float* o = out + (size_t)(p0 + i) * 768 + 4 * lane;

        vfloat4 r;
        r.x = fmaf(fmaf(h3[0], aa, cc), ga[0][0], be[0][0]);
        r.y = fmaf(fmaf(h3[1], aa, cc), ga[0][1], be[0][1]);
        r.z = fmaf(fmaf(h3[2], aa, cc), ga[0][2], be[0][2]);
        r.w = fmaf(fmaf(h3[3], aa, cc), ga[0][3], be[0][3]);
        *reinterpret_cast<vfloat4*>(o) = r;

        r.x = fmaf(fmaf(h5[0], aa, cc), ga[1][0], be[1][0]);
        r.y = fmaf(fmaf(h5[1], aa, cc), ga[1][1], be[1][1]);
        r.z = fmaf(fmaf(h5[2], aa, cc), ga[1][2], be[1][2]);
        r.w = fmaf(fmaf(h5[3], aa, cc), ga[1][3], be[1][3]);
        *reinterpret_cast<vfloat4*>(o + 256) = r;

        r.x = fmaf(fmaf(h7[0], aa, cc), ga[2][0], be[2][0]);
        r.y = fmaf(fmaf(h7[1], aa, cc), ga[2][1], be[2][1]);
        r.z = fmaf(fmaf(h7[2], aa, cc), ga[2][2], be[2][2]);
        r.w = fmaf(fmaf(h7[3], aa, cc), ga[2][3], be[2][3]);
        *reinterpret_cast<vfloat4*>(o + 512) = r;
    }
}

} // namespace

extern "C" void kernel_launch(void* const* d_in, const int* in_sizes, int n_in,
                              void* d_out, int out_size, void* d_ws, size_t ws_size,
                              hipStream_t stream) {
    const int*   ids   = (const int*)  d_in[0];
    const float* mask  = (const float*)d_in[1];
    const float* W3    = (const float*)d_in[2];
    const float* W5    = (const float*)d_in[3];
    const float* W7    = (const float*)d_in[4];
    const float* gamma = (const float*)d_in[5];
    const float* beta  = (const float*)d_in[6];
    float*       out   = (float*)d_out;

    const int npos = in_sizes[0];              // B*L = 65536
    const int grid = npos / kBlkPos;           // 512 blocks; 2/CU -> ONE clean round

    hipLaunchKernelGGL(cnn_emb_ln, dim3(grid), dim3(kThreads), 0, stream,
                       ids, mask, W3, W5, W7, gamma, beta, out);
}